// Round 5
// baseline (1684.253 us; speedup 1.0000x reference)
//
#include <hip/hip_runtime.h>
#include <hip/hip_bf16.h>
#include <hip/hip_fp16.h>

static __device__ __forceinline__ float ld(const float* p)  { return *p; }
static __device__ __forceinline__ float ld(const __half* p) { return __half2float(*p); }
static __device__ __forceinline__ void st(float* p, float v)  { *p = v; }
static __device__ __forceinline__ void st(__half* p, float v) { *p = __float2half(v); }

// ---------------- CSR build ----------------
__global__ void k_init(int* deg, float* gsum, int* cnt, int N, int G) {
    int i = blockIdx.x * blockDim.x + threadIdx.x;
    if (i < N) deg[i] = 1;              // self-loop
    if (i < G * 64) gsum[i] = 0.f;
    if (i < G) cnt[i] = 0;
}

__global__ void k_hist(const int* __restrict__ ei, int* deg, int E) {
    int e = blockIdx.x * blockDim.x + threadIdx.x;
    if (e < E) atomicAdd(&deg[ei[E + e]], 1);   // dst row of edge_index
}

__global__ void k_scan(const int* __restrict__ deg, int* offs, int* cursor, int N) {
    __shared__ int part[1024];
    int tid = threadIdx.x;
    int chunk = (N + 1023) >> 10;
    int s = tid * chunk, e = min(s + chunk, N);
    int sum = 0;
    for (int i = s; i < e; ++i) sum += deg[i];
    part[tid] = sum;
    __syncthreads();
    for (int off = 1; off < 1024; off <<= 1) {
        int v = (tid >= off) ? part[tid - off] : 0;
        __syncthreads();
        part[tid] += v;
        __syncthreads();
    }
    int run = part[tid] - sum;   // exclusive prefix
    for (int i = s; i < e; ++i) {
        int d = deg[i];
        offs[i] = run; cursor[i] = run; run += d;
    }
    if (tid == 1023) offs[N] = part[1023];
}

__global__ void k_scatter(const int* __restrict__ ei, int* cursor, int* csr, int E) {
    int e = blockIdx.x * blockDim.x + threadIdx.x;
    if (e < E) {
        int d = ei[E + e];
        int p = atomicAdd(&cursor[d], 1);
        csr[p] = ei[e];
    }
}

__global__ void k_scatter_loops(int* cursor, int* csr, int N) {
    int i = blockIdx.x * blockDim.x + threadIdx.x;
    if (i < N) { int p = atomicAdd(&cursor[i], 1); csr[p] = i; }
}

// ---------------- GEMM: C[nrows,M] = A[nrows,K] @ W[K,M], fp32 accumulate ----------------
template <typename AT, typename CT>
__global__ __launch_bounds__(256) void k_gemm(const AT* __restrict__ A, const float* __restrict__ W,
                                              CT* __restrict__ C, int nrows, int K, int M) {
    constexpr int BK = 32;
    __shared__ float As[BK][65];
    __shared__ float Bs[BK][65];
    int tid = threadIdx.x;
    int r0 = blockIdx.x * 64, c0 = blockIdx.y * 64;
    int tx = tid & 15, ty = tid >> 4;
    float acc[4][4] = {};
    for (int k0 = 0; k0 < K; k0 += BK) {
#pragma unroll
        for (int i = 0; i < 8; ++i) {
            int idx = tid + i * 256;
            int ar = idx >> 5, ak = idx & 31;
            int gr = r0 + ar;
            float v = 0.f;
            if (gr < nrows) v = ld(A + (size_t)gr * K + (k0 + ak));
            As[ak][ar] = v;
            int bc = idx & 63, bk = idx >> 6;
            Bs[bk][bc] = W[(size_t)(k0 + bk) * M + (c0 + bc)];
        }
        __syncthreads();
#pragma unroll
        for (int kk = 0; kk < BK; ++kk) {
            float a[4], b[4];
#pragma unroll
            for (int i = 0; i < 4; ++i) a[i] = As[kk][ty * 4 + i];
#pragma unroll
            for (int j = 0; j < 4; ++j) b[j] = Bs[kk][tx * 4 + j];
#pragma unroll
            for (int i = 0; i < 4; ++i)
#pragma unroll
                for (int j = 0; j < 4; ++j) acc[i][j] = fmaf(a[i], b[j], acc[i][j]);
        }
        __syncthreads();
    }
#pragma unroll
    for (int i = 0; i < 4; ++i) {
        int r = r0 + ty * 4 + i;
        if (r < nrows) {
#pragma unroll
            for (int j = 0; j < 4; ++j) st(&C[(size_t)r * M + c0 + tx * 4 + j], acc[i][j]);
        }
    }
}

// ---------------- attention coefficients: alpha[n,h] = dot(feat[n, h*64:(h+1)*64], a[h]) ----------------
template <int CHUNK, typename FT>
__global__ void k_alpha(const FT* __restrict__ feat, const float* __restrict__ a_src,
                        const float* __restrict__ a_dst, float* __restrict__ als,
                        float* __restrict__ ald, int N) {
    constexpr int M = 64 * CHUNK;
    constexpr int H = M / 64;
    constexpr int WIDTH = 64 / H;        // lanes per head
    int lane = threadIdx.x & 63;
    int node = blockIdx.x * 4 + (threadIdx.x >> 6);
    if (node >= N) return;
    const FT* row = feat + (size_t)node * M + lane * CHUNK;
    float ps = 0.f, pd = 0.f;
#pragma unroll
    for (int j = 0; j < CHUNK; ++j) {
        int col = lane * CHUNK + j;
        float f = ld(row + j);
        ps += f * a_src[col];
        pd += f * a_dst[col];
    }
#pragma unroll
    for (int off = 1; off < WIDTH; off <<= 1) {
        ps += __shfl_xor(ps, off, 64);
        pd += __shfl_xor(pd, off, 64);
    }
    if ((lane & (WIDTH - 1)) == 0) {
        int head = lane / WIDTH;
        als[(size_t)node * H + head] = ps;
        ald[(size_t)node * H + head] = pd;
    }
}

// ---------------- GAT aggregation: one wave per destination node ----------------
// out[dst] = (sum_e exp(e-m)*feat[src]) / (sum_e exp(e-m) + 1e-16) + bias [, ELU]
template <int CHUNK, bool ELU, typename FT, typename OT>
__global__ void k_agg(const FT* __restrict__ feat, const int* __restrict__ offs,
                      const int* __restrict__ csr, const float* __restrict__ als,
                      const float* __restrict__ ald, const float* __restrict__ bias,
                      OT* __restrict__ out, int N) {
    constexpr int M = 64 * CHUNK;
    constexpr int H = M / 64;
    int lane = threadIdx.x & 63;
    int node = blockIdx.x * 4 + (threadIdx.x >> 6);
    if (node >= N) return;
    int head = (CHUNK == 4) ? (lane >> 4) : 0;
    float ad = ald[(size_t)node * H + head];
    int beg = offs[node], end = offs[node + 1];

    // pass 1: segment max
    float m = -1e30f;
    for (int e = beg; e < end; ++e) {
        int s = csr[e];
        float x = als[(size_t)s * H + head] + ad;
        x = (x > 0.f) ? x : 0.2f * x;
        m = fmaxf(m, x);
    }
    // pass 2: fused exp-sum + weighted feature accumulate
    float den = 0.f;
    float acc[CHUNK];
#pragma unroll
    for (int j = 0; j < CHUNK; ++j) acc[j] = 0.f;
    for (int e = beg; e < end; ++e) {
        int s = csr[e];
        float x = als[(size_t)s * H + head] + ad;
        x = (x > 0.f) ? x : 0.2f * x;
        float w = expf(x - m);
        den += w;
        const FT* row = feat + (size_t)s * M + lane * CHUNK;
#pragma unroll
        for (int j = 0; j < CHUNK; ++j) acc[j] = fmaf(w, ld(row + j), acc[j]);
    }
    float inv = 1.f / (den + 1e-16f);
#pragma unroll
    for (int j = 0; j < CHUNK; ++j) {
        int col = lane * CHUNK + j;
        float v = acc[j] * inv + bias[col];
        if (ELU) v = (v > 0.f) ? v : (expf(v) - 1.f);
        st(&out[(size_t)node * M + col], v);
    }
}

// ---------------- global mean pool (reads fp32 node embeddings from d_out) ----------------
__global__ void k_pool(const float* __restrict__ ne, const int* __restrict__ batch,
                       float* gsum, int* cnt, int N) {
    int lane = threadIdx.x & 63;
    int node = blockIdx.x * 4 + (threadIdx.x >> 6);
    if (node >= N) return;
    int g = batch[node];
    atomicAdd(&gsum[(size_t)g * 64 + lane], ne[(size_t)node * 64 + lane]);
    if (lane == 0) atomicAdd(&cnt[g], 1);
}

__global__ void k_gfinal(const float* __restrict__ gsum, const int* __restrict__ cnt,
                         float* __restrict__ out, int G) {
    int i = blockIdx.x * blockDim.x + threadIdx.x;
    if (i < G * 64) {
        int g = i >> 6;
        float c = (float)cnt[g];
        out[i] = gsum[i] / fmaxf(c, 1.f);
    }
}

// ---------------- pipeline, templated on intermediate storage type ----------------
template <typename FT>
static void run_all(const float* x, const int* ei, const int* batch,
                    const float* W1, const float* as1, const float* ad1, const float* b1,
                    const float* W2, const float* as2, const float* ad2, const float* b2,
                    const float* W3, const float* as3, const float* ad3, const float* b3,
                    float* out, void* d_ws, int N, int E, int G, hipStream_t stream) {
    char* w = (char*)d_ws;
    auto carve = [&](size_t bytes) { char* p = w; w += (bytes + 255) & ~(size_t)255; return p; };
    FT* feat    = (FT*)carve((size_t)N * 256 * sizeof(FT));
    FT* act     = (FT*)carve((size_t)N * 256 * sizeof(FT));
    float* als  = (float*)carve((size_t)N * 4 * 4);
    float* ald  = (float*)carve((size_t)N * 4 * 4);
    float* gsum = (float*)carve((size_t)G * 64 * 4);
    int* cnt    = (int*)carve((size_t)G * 4);
    int* deg    = (int*)carve((size_t)N * 4);
    int* offs   = (int*)carve((size_t)(N + 1) * 4);
    int* cursor = (int*)carve((size_t)N * 4);
    int* csr    = (int*)carve((size_t)(E + N) * 4);

    k_init<<<(N + 255) / 256, 256, 0, stream>>>(deg, gsum, cnt, N, G);
    k_hist<<<(E + 255) / 256, 256, 0, stream>>>(ei, deg, E);
    k_scan<<<1, 1024, 0, stream>>>(deg, offs, cursor, N);
    k_scatter<<<(E + 255) / 256, 256, 0, stream>>>(ei, cursor, csr, E);
    k_scatter_loops<<<(N + 255) / 256, 256, 0, stream>>>(cursor, csr, N);

    dim3 gBig((N + 63) / 64, 4);
    dim3 gSmall((N + 63) / 64, 1);
    int nodeBlocks = (N + 3) / 4;

    // layer 1: x @ W1 -> feat; attention; aggregate+bias+ELU -> act
    k_gemm<float, FT><<<gBig, 256, 0, stream>>>(x, W1, feat, N, 256, 256);
    k_alpha<4, FT><<<nodeBlocks, 256, 0, stream>>>(feat, as1, ad1, als, ald, N);
    k_agg<4, true, FT, FT><<<nodeBlocks, 256, 0, stream>>>(feat, offs, csr, als, ald, b1, act, N);
    // layer 2
    k_gemm<FT, FT><<<gBig, 256, 0, stream>>>(act, W2, feat, N, 256, 256);
    k_alpha<4, FT><<<nodeBlocks, 256, 0, stream>>>(feat, as2, ad2, als, ald, N);
    k_agg<4, true, FT, FT><<<nodeBlocks, 256, 0, stream>>>(feat, offs, csr, als, ald, b2, act, N);
    // layer 3: 256 -> 64, single head, no ELU; fp32 node embeddings straight to d_out
    k_gemm<FT, FT><<<gSmall, 256, 0, stream>>>(act, W3, feat, N, 256, 64);
    k_alpha<1, FT><<<nodeBlocks, 256, 0, stream>>>(feat, as3, ad3, als, ald, N);
    k_agg<1, false, FT, float><<<nodeBlocks, 256, 0, stream>>>(feat, offs, csr, als, ald, b3, out, N);

    // global mean pool
    k_pool<<<nodeBlocks, 256, 0, stream>>>(out, batch, gsum, cnt, N);
    k_gfinal<<<(G * 64 + 255) / 256, 256, 0, stream>>>(gsum, cnt, out + (size_t)N * 64, G);
}

extern "C" void kernel_launch(void* const* d_in, const int* in_sizes, int n_in,
                              void* d_out, int out_size, void* d_ws, size_t ws_size,
                              hipStream_t stream) {
    const float* x   = (const float*)d_in[0];
    const int* ei    = (const int*)d_in[1];
    const int* batch = (const int*)d_in[2];
    const float* W1  = (const float*)d_in[3];
    const float* as1 = (const float*)d_in[4];
    const float* ad1 = (const float*)d_in[5];
    const float* b1  = (const float*)d_in[6];
    const float* W2  = (const float*)d_in[7];
    const float* as2 = (const float*)d_in[8];
    const float* ad2 = (const float*)d_in[9];
    const float* b2  = (const float*)d_in[10];
    const float* W3  = (const float*)d_in[11];
    const float* as3 = (const float*)d_in[12];
    const float* ad3 = (const float*)d_in[13];
    const float* b3  = (const float*)d_in[14];

    const int N = in_sizes[2];      // 50000
    const int E = in_sizes[1] / 2;  // 800000
    const int G = 64;
    float* out = (float*)d_out;

    // fp32 intermediates need ~108 MB of ws; fall back to fp16 (~57 MB) if ws is smaller.
    size_t need_f32 = (size_t)N * 256 * 4 * 2 + (size_t)N * 4 * 4 * 2 + (size_t)(G * 64 + G) * 4
                    + (size_t)N * 4 * 3 + (size_t)(E + N + 1) * 4 + 4096;
    if (ws_size >= need_f32)
        run_all<float >(x, ei, batch, W1, as1, ad1, b1, W2, as2, ad2, b2, W3, as3, ad3, b3,
                        out, d_ws, N, E, G, stream);
    else
        run_all<__half>(x, ei, batch, W1, as1, ad1, b1, W2, as2, ad2, b2, W3, as3, ad3, b3,
                        out, d_ws, N, E, G, stream);
}

// Round 6
// 1322.526 us; speedup vs baseline: 1.2735x; 1.2735x over previous
//
#include <hip/hip_runtime.h>
#include <hip/hip_bf16.h>
#include <hip/hip_fp16.h>

static __device__ __forceinline__ float ld(const float* p)  { return *p; }
static __device__ __forceinline__ float ld(const __half* p) { return __half2float(*p); }
static __device__ __forceinline__ void st(float* p, float v)  { *p = v; }
static __device__ __forceinline__ void st(__half* p, float v) { *p = __float2half(v); }

// vectorized row loaders (CHUNK consecutive channels per lane)
static __device__ __forceinline__ void ldrow4(const float* p, float* f) {
    float4 v = *reinterpret_cast<const float4*>(p);
    f[0] = v.x; f[1] = v.y; f[2] = v.z; f[3] = v.w;
}
static __device__ __forceinline__ void ldrow4(const __half* p, float* f) {
    const __half2* q = reinterpret_cast<const __half2*>(p);
    float2 a = __half22float2(q[0]), b = __half22float2(q[1]);
    f[0] = a.x; f[1] = a.y; f[2] = b.x; f[3] = b.y;
}
static __device__ __forceinline__ void ldrow1(const float* p, float* f)  { f[0] = *p; }
static __device__ __forceinline__ void ldrow1(const __half* p, float* f) { f[0] = __half2float(*p); }
template <int CHUNK, typename FT>
static __device__ __forceinline__ void ldrow(const FT* p, float* f) {
    if constexpr (CHUNK == 4) ldrow4(p, f); else ldrow1(p, f);
}

// ---------------- CSR build ----------------
__global__ void k_init(int* deg, int N) {
    int i = blockIdx.x * blockDim.x + threadIdx.x;
    if (i < N) deg[i] = 1;              // self-loop
}

__global__ void k_hist(const int* __restrict__ ei, int* deg, int E) {
    int e = blockIdx.x * blockDim.x + threadIdx.x;
    if (e < E) atomicAdd(&deg[ei[E + e]], 1);   // dst row of edge_index
}

__global__ void k_scan(const int* __restrict__ deg, int* offs, int* cursor, int N) {
    __shared__ int part[1024];
    int tid = threadIdx.x;
    int chunk = (N + 1023) >> 10;
    int s = tid * chunk, e = min(s + chunk, N);
    int sum = 0;
    for (int i = s; i < e; ++i) sum += deg[i];
    part[tid] = sum;
    __syncthreads();
    for (int off = 1; off < 1024; off <<= 1) {
        int v = (tid >= off) ? part[tid - off] : 0;
        __syncthreads();
        part[tid] += v;
        __syncthreads();
    }
    int run = part[tid] - sum;   // exclusive prefix
    for (int i = s; i < e; ++i) {
        int d = deg[i];
        offs[i] = run; cursor[i] = run; run += d;
    }
    if (tid == 1023) offs[N] = part[1023];
}

__global__ void k_scatter(const int* __restrict__ ei, int* cursor, int* csr, int E) {
    int e = blockIdx.x * blockDim.x + threadIdx.x;
    if (e < E) {
        int d = ei[E + e];
        int p = atomicAdd(&cursor[d], 1);
        csr[p] = ei[e];
    }
}

__global__ void k_scatter_loops(int* cursor, int* csr, int N) {
    int i = blockIdx.x * blockDim.x + threadIdx.x;
    if (i < N) { int p = atomicAdd(&cursor[i], 1); csr[p] = i; }
}

// ---------------- GEMM: C[nrows,M] = A[nrows,K] @ W[K,M], fp32 accumulate ----------------
template <typename AT, typename CT>
__global__ __launch_bounds__(256) void k_gemm(const AT* __restrict__ A, const float* __restrict__ W,
                                              CT* __restrict__ C, int nrows, int K, int M) {
    constexpr int BK = 32;
    __shared__ float As[BK][65];
    __shared__ float Bs[BK][65];
    int tid = threadIdx.x;
    int r0 = blockIdx.x * 64, c0 = blockIdx.y * 64;
    int tx = tid & 15, ty = tid >> 4;
    float acc[4][4] = {};
    for (int k0 = 0; k0 < K; k0 += BK) {
#pragma unroll
        for (int i = 0; i < 8; ++i) {
            int idx = tid + i * 256;
            int ar = idx >> 5, ak = idx & 31;
            int gr = r0 + ar;
            float v = 0.f;
            if (gr < nrows) v = ld(A + (size_t)gr * K + (k0 + ak));
            As[ak][ar] = v;
            int bc = idx & 63, bk = idx >> 6;
            Bs[bk][bc] = W[(size_t)(k0 + bk) * M + (c0 + bc)];
        }
        __syncthreads();
#pragma unroll
        for (int kk = 0; kk < BK; ++kk) {
            float a[4], b[4];
#pragma unroll
            for (int i = 0; i < 4; ++i) a[i] = As[kk][ty * 4 + i];
#pragma unroll
            for (int j = 0; j < 4; ++j) b[j] = Bs[kk][tx * 4 + j];
#pragma unroll
            for (int i = 0; i < 4; ++i)
#pragma unroll
                for (int j = 0; j < 4; ++j) acc[i][j] = fmaf(a[i], b[j], acc[i][j]);
        }
        __syncthreads();
    }
#pragma unroll
    for (int i = 0; i < 4; ++i) {
        int r = r0 + ty * 4 + i;
        if (r < nrows) {
#pragma unroll
            for (int j = 0; j < 4; ++j) st(&C[(size_t)r * M + c0 + tx * 4 + j], acc[i][j]);
        }
    }
}

// ---------------- attention coefficients: alpha[n,h] = dot(feat[n, h*64:(h+1)*64], a[h]) ----------------
template <int CHUNK, typename FT>
__global__ void k_alpha(const FT* __restrict__ feat, const float* __restrict__ a_src,
                        const float* __restrict__ a_dst, float* __restrict__ als,
                        float* __restrict__ ald, int N) {
    constexpr int M = 64 * CHUNK;
    constexpr int H = M / 64;
    constexpr int WIDTH = 64 / H;        // lanes per head
    int lane = threadIdx.x & 63;
    int node = blockIdx.x * 4 + (threadIdx.x >> 6);
    if (node >= N) return;
    float f[CHUNK];
    ldrow<CHUNK>(feat + (size_t)node * M + lane * CHUNK, f);
    float ps = 0.f, pd = 0.f;
#pragma unroll
    for (int j = 0; j < CHUNK; ++j) {
        int col = lane * CHUNK + j;
        ps += f[j] * a_src[col];
        pd += f[j] * a_dst[col];
    }
#pragma unroll
    for (int off = 1; off < WIDTH; off <<= 1) {
        ps += __shfl_xor(ps, off, 64);
        pd += __shfl_xor(pd, off, 64);
    }
    if ((lane & (WIDTH - 1)) == 0) {
        int head = lane / WIDTH;
        als[(size_t)node * H + head] = ps;
        ald[(size_t)node * H + head] = pd;
    }
}

// ---------------- segment max + denominator: 16 lanes per node, edge-parallel ----------------
template <int H>
__global__ void k_maxden(const int* __restrict__ offs, const int* __restrict__ csr,
                         const float* __restrict__ als, const float* __restrict__ ald,
                         float* __restrict__ minv, float* __restrict__ dinv, int N) {
    int sub  = threadIdx.x & 15;
    int node = blockIdx.x * 16 + (threadIdx.x >> 4);
    if (node >= N) return;
    constexpr int ES = (H == 4) ? 4 : 16;         // edge stride
    int h    = (H == 4) ? (sub & 3) : 0;
    int eoff = (H == 4) ? (sub >> 2) : sub;
    float ad = ald[(size_t)node * H + h];
    int beg = offs[node], end = offs[node + 1];

    float mm = -1e30f;
    for (int e = beg + eoff; e < end; e += ES) {
        int s = csr[e];
        float x = als[(size_t)s * H + h] + ad;
        x = (x > 0.f) ? x : 0.2f * x;
        mm = fmaxf(mm, x);
    }
    if (H == 4) {
        mm = fmaxf(mm, __shfl_xor(mm, 4, 64));
        mm = fmaxf(mm, __shfl_xor(mm, 8, 64));
    } else {
#pragma unroll
        for (int off = 1; off < 16; off <<= 1) mm = fmaxf(mm, __shfl_xor(mm, off, 64));
    }
    float den = 0.f;
    for (int e = beg + eoff; e < end; e += ES) {
        int s = csr[e];
        float x = als[(size_t)s * H + h] + ad;
        x = (x > 0.f) ? x : 0.2f * x;
        den += __expf(x - mm);
    }
    if (H == 4) {
        den += __shfl_xor(den, 4, 64);
        den += __shfl_xor(den, 8, 64);
    } else {
#pragma unroll
        for (int off = 1; off < 16; off <<= 1) den += __shfl_xor(den, off, 64);
    }
    if (eoff == 0) {
        minv[(size_t)node * H + h] = mm;
        dinv[(size_t)node * H + h] = 1.f / (den + 1e-16f);
    }
}

// ---------------- GAT aggregation: one wave per destination node, single pass, prefetched ----------------
template <int CHUNK, bool ELU, typename FT, typename OT>
__global__ void k_agg(const FT* __restrict__ feat, const int* __restrict__ offs,
                      const int* __restrict__ csr, const float* __restrict__ als,
                      const float* __restrict__ ald, const float* __restrict__ minv,
                      const float* __restrict__ dinv, const float* __restrict__ bias,
                      OT* __restrict__ out, int N) {
    constexpr int M = 64 * CHUNK;
    constexpr int H = M / 64;
    int lane = threadIdx.x & 63;
    int node = blockIdx.x * 4 + (threadIdx.x >> 6);
    if (node >= N) return;
    int head = (CHUNK == 4) ? (lane >> 4) : 0;
    float ad  = ald[(size_t)node * H + head];
    float m   = minv[(size_t)node * H + head];
    float inv = dinv[(size_t)node * H + head];
    int beg = offs[node], end = offs[node + 1];

    float acc[CHUNK] = {};
    // software pipeline: edge e's csr/als/feat-row loaded during iteration e-1
    int   s0 = csr[beg];
    float x0 = als[(size_t)s0 * H + head];
    float f0[CHUNK];
    ldrow<CHUNK>(feat + (size_t)s0 * M + lane * CHUNK, f0);
    for (int e = beg; e < end - 1; ++e) {
        int   s1 = csr[e + 1];
        float x1 = als[(size_t)s1 * H + head];
        float f1[CHUNK];
        ldrow<CHUNK>(feat + (size_t)s1 * M + lane * CHUNK, f1);
        float x = x0 + ad;
        x = (x > 0.f) ? x : 0.2f * x;
        float w = __expf(x - m);
#pragma unroll
        for (int j = 0; j < CHUNK; ++j) acc[j] = fmaf(w, f0[j], acc[j]);
        x0 = x1;
#pragma unroll
        for (int j = 0; j < CHUNK; ++j) f0[j] = f1[j];
    }
    {   // last edge
        float x = x0 + ad;
        x = (x > 0.f) ? x : 0.2f * x;
        float w = __expf(x - m);
#pragma unroll
        for (int j = 0; j < CHUNK; ++j) acc[j] = fmaf(w, f0[j], acc[j]);
    }
#pragma unroll
    for (int j = 0; j < CHUNK; ++j) {
        int col = lane * CHUNK + j;
        float v = acc[j] * inv + bias[col];
        if (ELU) v = (v > 0.f) ? v : (__expf(v) - 1.f);
        st(&out[(size_t)node * M + col], v);
    }
}

// ---------------- global mean pool: batch is sorted -> one block per graph, zero atomics ----------------
static __device__ __forceinline__ int lowerb(const int* __restrict__ a, int n, int v) {
    int lo = 0, hi = n;
    while (lo < hi) { int mid = (lo + hi) >> 1; if (a[mid] < v) lo = mid + 1; else hi = mid; }
    return lo;
}

__global__ void k_pool2(const float* __restrict__ ne, const int* __restrict__ batch,
                        float* __restrict__ gout, int N) {
    int g = blockIdx.x;
    int lo = lowerb(batch, N, g);
    int hi = lowerb(batch, N, g + 1);
    int lane = threadIdx.x & 63, row = threadIdx.x >> 6;
    float s = 0.f;
    for (int i = lo + row; i < hi; i += 4) s += ne[(size_t)i * 64 + lane];
    __shared__ float red[4][64];
    red[row][lane] = s;
    __syncthreads();
    if (row == 0) {
        float v = red[0][lane] + red[1][lane] + red[2][lane] + red[3][lane];
        gout[(size_t)g * 64 + lane] = v / fmaxf((float)(hi - lo), 1.f);
    }
}

// ---------------- pipeline, templated on intermediate storage type ----------------
template <typename FT>
static void run_all(const float* x, const int* ei, const int* batch,
                    const float* W1, const float* as1, const float* ad1, const float* b1,
                    const float* W2, const float* as2, const float* ad2, const float* b2,
                    const float* W3, const float* as3, const float* ad3, const float* b3,
                    float* out, void* d_ws, int N, int E, int G, hipStream_t stream) {
    char* w = (char*)d_ws;
    auto carve = [&](size_t bytes) { char* p = w; w += (bytes + 255) & ~(size_t)255; return p; };
    FT* feat    = (FT*)carve((size_t)N * 256 * sizeof(FT));
    FT* act     = (FT*)carve((size_t)N * 256 * sizeof(FT));
    float* als  = (float*)carve((size_t)N * 4 * 4);
    float* ald  = (float*)carve((size_t)N * 4 * 4);
    float* minv = (float*)carve((size_t)N * 4 * 4);
    float* dinv = (float*)carve((size_t)N * 4 * 4);
    int* deg    = (int*)carve((size_t)N * 4);
    int* offs   = (int*)carve((size_t)(N + 1) * 4);
    int* cursor = (int*)carve((size_t)N * 4);
    int* csr    = (int*)carve((size_t)(E + N) * 4);

    k_init<<<(N + 255) / 256, 256, 0, stream>>>(deg, N);
    k_hist<<<(E + 255) / 256, 256, 0, stream>>>(ei, deg, E);
    k_scan<<<1, 1024, 0, stream>>>(deg, offs, cursor, N);
    k_scatter<<<(E + 255) / 256, 256, 0, stream>>>(ei, cursor, csr, E);
    k_scatter_loops<<<(N + 255) / 256, 256, 0, stream>>>(cursor, csr, N);

    dim3 gBig((N + 63) / 64, 4);
    dim3 gSmall((N + 63) / 64, 1);
    int nodeBlocks = (N + 3) / 4;
    int mdBlocks   = (N + 15) / 16;

    // layer 1: x @ W1 -> feat; attention; aggregate+bias+ELU -> act
    k_gemm<float, FT><<<gBig, 256, 0, stream>>>(x, W1, feat, N, 256, 256);
    k_alpha<4, FT><<<nodeBlocks, 256, 0, stream>>>(feat, as1, ad1, als, ald, N);
    k_maxden<4><<<mdBlocks, 256, 0, stream>>>(offs, csr, als, ald, minv, dinv, N);
    k_agg<4, true, FT, FT><<<nodeBlocks, 256, 0, stream>>>(feat, offs, csr, als, ald, minv, dinv, b1, act, N);
    // layer 2
    k_gemm<FT, FT><<<gBig, 256, 0, stream>>>(act, W2, feat, N, 256, 256);
    k_alpha<4, FT><<<nodeBlocks, 256, 0, stream>>>(feat, as2, ad2, als, ald, N);
    k_maxden<4><<<mdBlocks, 256, 0, stream>>>(offs, csr, als, ald, minv, dinv, N);
    k_agg<4, true, FT, FT><<<nodeBlocks, 256, 0, stream>>>(feat, offs, csr, als, ald, minv, dinv, b2, act, N);
    // layer 3: 256 -> 64, single head, no ELU; fp32 node embeddings straight to d_out
    k_gemm<FT, FT><<<gSmall, 256, 0, stream>>>(act, W3, feat, N, 256, 64);
    k_alpha<1, FT><<<nodeBlocks, 256, 0, stream>>>(feat, as3, ad3, als, ald, N);
    k_maxden<1><<<mdBlocks, 256, 0, stream>>>(offs, csr, als, ald, minv, dinv, N);
    k_agg<1, false, FT, float><<<nodeBlocks, 256, 0, stream>>>(feat, offs, csr, als, ald, minv, dinv, b3, out, N);

    // global mean pool: one block per graph, no atomics (batch sorted)
    k_pool2<<<G, 256, 0, stream>>>(out, batch, out + (size_t)N * 64, N);
}

extern "C" void kernel_launch(void* const* d_in, const int* in_sizes, int n_in,
                              void* d_out, int out_size, void* d_ws, size_t ws_size,
                              hipStream_t stream) {
    const float* x   = (const float*)d_in[0];
    const int* ei    = (const int*)d_in[1];
    const int* batch = (const int*)d_in[2];
    const float* W1  = (const float*)d_in[3];
    const float* as1 = (const float*)d_in[4];
    const float* ad1 = (const float*)d_in[5];
    const float* b1  = (const float*)d_in[6];
    const float* W2  = (const float*)d_in[7];
    const float* as2 = (const float*)d_in[8];
    const float* ad2 = (const float*)d_in[9];
    const float* b2  = (const float*)d_in[10];
    const float* W3  = (const float*)d_in[11];
    const float* as3 = (const float*)d_in[12];
    const float* ad3 = (const float*)d_in[13];
    const float* b3  = (const float*)d_in[14];

    const int N = in_sizes[2];      // 50000
    const int E = in_sizes[1] / 2;  // 800000
    const int G = 64;
    float* out = (float*)d_out;

    // fp32 intermediates need ~107 MB of ws; fall back to fp16 (~56 MB) if ws is smaller.
    size_t need_f32 = (size_t)N * 256 * 4 * 2      // feat + act
                    + (size_t)N * 4 * 4 * 4        // als, ald, minv, dinv
                    + (size_t)N * 4 * 3            // deg, cursor, + offs (approx)
                    + (size_t)(E + N + 1) * 4      // csr
                    + 8192;
    if (ws_size >= need_f32)
        run_all<float >(x, ei, batch, W1, as1, ad1, b1, W2, as2, ad2, b2, W3, as3, ad3, b3,
                        out, d_ws, N, E, G, stream);
    else
        run_all<__half>(x, ei, batch, W1, as1, ad1, b1, W2, as2, ad2, b2, W3, as3, ad3, b3,
                        out, d_ws, N, E, G, stream);
}

// Round 7
// 858.218 us; speedup vs baseline: 1.9625x; 1.5410x over previous
//
#include <hip/hip_runtime.h>
#include <hip/hip_bf16.h>
#include <hip/hip_fp16.h>

typedef __attribute__((ext_vector_type(8))) short bf16x8;
typedef __attribute__((ext_vector_type(4))) float f32x4;

static __device__ __forceinline__ float ld(const float* p)  { return *p; }
static __device__ __forceinline__ float ld(const __half* p) { return __half2float(*p); }
static __device__ __forceinline__ void st(float* p, float v)  { *p = v; }
static __device__ __forceinline__ void st(__half* p, float v) { *p = __float2half(v); }

// fp32 -> bf16 RNE on raw bits
static __device__ __forceinline__ unsigned short f2bf(float f) {
    unsigned int u = __builtin_bit_cast(unsigned int, f);
    unsigned int r = u + 0x7FFFu + ((u >> 16) & 1u);
    return (unsigned short)(r >> 16);
}
static __device__ __forceinline__ float bf2f(unsigned short h) {
    unsigned int u = ((unsigned int)h) << 16;
    return __builtin_bit_cast(float, u);
}
static __device__ __forceinline__ void split(float v, unsigned short& hi, unsigned short& lo) {
    hi = f2bf(v);
    lo = f2bf(v - bf2f(hi));
}

// vectorized row loaders (CHUNK consecutive channels per lane)
static __device__ __forceinline__ void ldrow4(const float* p, float* f) {
    float4 v = *reinterpret_cast<const float4*>(p);
    f[0] = v.x; f[1] = v.y; f[2] = v.z; f[3] = v.w;
}
static __device__ __forceinline__ void ldrow4(const __half* p, float* f) {
    const __half2* q = reinterpret_cast<const __half2*>(p);
    float2 a = __half22float2(q[0]), b = __half22float2(q[1]);
    f[0] = a.x; f[1] = a.y; f[2] = b.x; f[3] = b.y;
}
static __device__ __forceinline__ void ldrow1(const float* p, float* f)  { f[0] = *p; }
static __device__ __forceinline__ void ldrow1(const __half* p, float* f) { f[0] = __half2float(*p); }
template <int CHUNK, typename FT>
static __device__ __forceinline__ void ldrow(const FT* p, float* f) {
    if constexpr (CHUNK == 4) ldrow4(p, f); else ldrow1(p, f);
}

// ---------------- CSR build ----------------
__global__ void k_init(int* deg, int N) {
    int i = blockIdx.x * blockDim.x + threadIdx.x;
    if (i < N) deg[i] = 1;              // self-loop
}

__global__ void k_hist(const int* __restrict__ ei, int* deg, int E) {
    int e = blockIdx.x * blockDim.x + threadIdx.x;
    if (e < E) atomicAdd(&deg[ei[E + e]], 1);
}

__global__ void k_scan(const int* __restrict__ deg, int* offs, int* cursor, int N) {
    __shared__ int part[1024];
    int tid = threadIdx.x;
    int chunk = (N + 1023) >> 10;
    int s = tid * chunk, e = min(s + chunk, N);
    int sum = 0;
    for (int i = s; i < e; ++i) sum += deg[i];
    part[tid] = sum;
    __syncthreads();
    for (int off = 1; off < 1024; off <<= 1) {
        int v = (tid >= off) ? part[tid - off] : 0;
        __syncthreads();
        part[tid] += v;
        __syncthreads();
    }
    int run = part[tid] - sum;
    for (int i = s; i < e; ++i) {
        int d = deg[i];
        offs[i] = run; cursor[i] = run; run += d;
    }
    if (tid == 1023) offs[N] = part[1023];
}

__global__ void k_scatter(const int* __restrict__ ei, int* cursor, int* csr, int E) {
    int e = blockIdx.x * blockDim.x + threadIdx.x;
    if (e < E) {
        int d = ei[E + e];
        int p = atomicAdd(&cursor[d], 1);
        csr[p] = ei[e];
    }
}

__global__ void k_scatter_loops(int* cursor, int* csr, int N) {
    int i = blockIdx.x * blockDim.x + threadIdx.x;
    if (i < N) { int p = atomicAdd(&cursor[i], 1); csr[p] = i; }
}

// ---------------- split-bf16 MFMA GEMM ----------------
// C[nrows,M](f16) = A[nrows,K] @ W[K,M](fp32), via A=Ah+Al, B=Bh+Bl (bf16):
// D += Ah*Bh + Ah*Bl + Al*Bh  (lo*lo term ~2^-16, dropped).
// BM=128, BN=64, BK=64; 256 threads = 4 waves in 2x2; wave tile 64x32 = 4x2 MFMA tiles.
// LDS rows padded to 72 shorts (144B, 16B-aligned) to break stride-128 bank conflicts.
template <typename AT>
__global__ __launch_bounds__(256) void k_gemm_mfma(const AT* __restrict__ A, const float* __restrict__ W,
                                                   __half* __restrict__ C, int nrows, int K, int M) {
    constexpr int LDA = 72;   // row stride (shorts) for 64-wide k
    __shared__ unsigned short AH[128 * LDA];
    __shared__ unsigned short AL[128 * LDA];
    __shared__ unsigned short BH[64 * LDA];   // stored transposed: [n][k]
    __shared__ unsigned short BL[64 * LDA];

    int tid  = threadIdx.x;
    int lane = tid & 63;
    int wave = tid >> 6;
    int wr = wave & 1, wc = wave >> 1;        // wave grid 2x2
    int quad = lane >> 4, r = lane & 15;
    int r0 = blockIdx.x * 128, c0 = blockIdx.y * 64;

    f32x4 acc[4][2];
#pragma unroll
    for (int i = 0; i < 4; ++i)
#pragma unroll
        for (int j = 0; j < 2; ++j) acc[i][j] = (f32x4){0.f, 0.f, 0.f, 0.f};

    for (int kc = 0; kc < K; kc += 64) {
        // ---- stage A: 128 rows x 64 k, split to hi/lo ----
#pragma unroll
        for (int it = 0; it < 4; ++it) {
            int row  = (tid >> 3) + it * 32;
            int kseg = (tid & 7) * 8;
            int gr = r0 + row;
            unsigned short h[8], l[8];
            if (gr < nrows) {
                const AT* src = A + (size_t)gr * K + kc + kseg;
#pragma unroll
                for (int j = 0; j < 8; ++j) split(ld(src + j), h[j], l[j]);
            } else {
#pragma unroll
                for (int j = 0; j < 8; ++j) { h[j] = 0; l[j] = 0; }
            }
            *reinterpret_cast<bf16x8*>(&AH[row * LDA + kseg]) = *reinterpret_cast<bf16x8*>(h);
            *reinterpret_cast<bf16x8*>(&AL[row * LDA + kseg]) = *reinterpret_cast<bf16x8*>(l);
        }
        // ---- stage B: 64 k x 64 n from W (row-major), transposed into [n][k] ----
#pragma unroll
        for (int it = 0; it < 4; ++it) {
            int kk = (tid >> 4) + it * 16;
            int n4 = (tid & 15) * 4;
            float4 v = *reinterpret_cast<const float4*>(W + (size_t)(kc + kk) * M + c0 + n4);
            float f[4] = {v.x, v.y, v.z, v.w};
#pragma unroll
            for (int j = 0; j < 4; ++j) {
                unsigned short h, l;
                split(f[j], h, l);
                BH[(n4 + j) * LDA + kk] = h;
                BL[(n4 + j) * LDA + kk] = l;
            }
        }
        __syncthreads();
        // ---- compute: two 16x16x32 k-steps ----
#pragma unroll
        for (int ks = 0; ks < 2; ++ks) {
            int k0 = ks * 32 + quad * 8;
            bf16x8 ah[4], al[4], bh[2], bl[2];
#pragma unroll
            for (int tr = 0; tr < 4; ++tr) {
                int row = wr * 64 + tr * 16 + r;
                ah[tr] = *reinterpret_cast<const bf16x8*>(&AH[row * LDA + k0]);
                al[tr] = *reinterpret_cast<const bf16x8*>(&AL[row * LDA + k0]);
            }
#pragma unroll
            for (int tc = 0; tc < 2; ++tc) {
                int col = wc * 32 + tc * 16 + r;
                bh[tc] = *reinterpret_cast<const bf16x8*>(&BH[col * LDA + k0]);
                bl[tc] = *reinterpret_cast<const bf16x8*>(&BL[col * LDA + k0]);
            }
#pragma unroll
            for (int tr = 0; tr < 4; ++tr)
#pragma unroll
                for (int tc = 0; tc < 2; ++tc) {
                    acc[tr][tc] = __builtin_amdgcn_mfma_f32_16x16x32_bf16(ah[tr], bh[tc], acc[tr][tc], 0, 0, 0);
                    acc[tr][tc] = __builtin_amdgcn_mfma_f32_16x16x32_bf16(ah[tr], bl[tc], acc[tr][tc], 0, 0, 0);
                    acc[tr][tc] = __builtin_amdgcn_mfma_f32_16x16x32_bf16(al[tr], bh[tc], acc[tr][tc], 0, 0, 0);
                }
        }
        __syncthreads();
    }
    // ---- epilogue: D lane mapping col=lane&15, row=quad*4+reg ----
#pragma unroll
    for (int tr = 0; tr < 4; ++tr)
#pragma unroll
        for (int tc = 0; tc < 2; ++tc) {
            int col = c0 + wc * 32 + tc * 16 + r;
#pragma unroll
            for (int i = 0; i < 4; ++i) {
                int row = r0 + wr * 64 + tr * 16 + quad * 4 + i;
                if (row < nrows) C[(size_t)row * M + col] = __float2half(acc[tr][tc][i]);
            }
        }
}

// ---------------- attention coefficients ----------------
template <int CHUNK, typename FT>
__global__ void k_alpha(const FT* __restrict__ feat, const float* __restrict__ a_src,
                        const float* __restrict__ a_dst, float* __restrict__ als,
                        float* __restrict__ ald, int N) {
    constexpr int M = 64 * CHUNK;
    constexpr int H = M / 64;
    constexpr int WIDTH = 64 / H;
    int lane = threadIdx.x & 63;
    int node = blockIdx.x * 4 + (threadIdx.x >> 6);
    if (node >= N) return;
    float f[CHUNK];
    ldrow<CHUNK>(feat + (size_t)node * M + lane * CHUNK, f);
    float ps = 0.f, pd = 0.f;
#pragma unroll
    for (int j = 0; j < CHUNK; ++j) {
        int col = lane * CHUNK + j;
        ps += f[j] * a_src[col];
        pd += f[j] * a_dst[col];
    }
#pragma unroll
    for (int off = 1; off < WIDTH; off <<= 1) {
        ps += __shfl_xor(ps, off, 64);
        pd += __shfl_xor(pd, off, 64);
    }
    if ((lane & (WIDTH - 1)) == 0) {
        int head = lane / WIDTH;
        als[(size_t)node * H + head] = ps;
        ald[(size_t)node * H + head] = pd;
    }
}

// ---------------- segment max + denominator ----------------
template <int H>
__global__ void k_maxden(const int* __restrict__ offs, const int* __restrict__ csr,
                         const float* __restrict__ als, const float* __restrict__ ald,
                         float* __restrict__ minv, float* __restrict__ dinv, int N) {
    int sub  = threadIdx.x & 15;
    int node = blockIdx.x * 16 + (threadIdx.x >> 4);
    if (node >= N) return;
    constexpr int ES = (H == 4) ? 4 : 16;
    int h    = (H == 4) ? (sub & 3) : 0;
    int eoff = (H == 4) ? (sub >> 2) : sub;
    float ad = ald[(size_t)node * H + h];
    int beg = offs[node], end = offs[node + 1];

    float mm = -1e30f;
    for (int e = beg + eoff; e < end; e += ES) {
        int s = csr[e];
        float x = als[(size_t)s * H + h] + ad;
        x = (x > 0.f) ? x : 0.2f * x;
        mm = fmaxf(mm, x);
    }
    if (H == 4) {
        mm = fmaxf(mm, __shfl_xor(mm, 4, 64));
        mm = fmaxf(mm, __shfl_xor(mm, 8, 64));
    } else {
#pragma unroll
        for (int off = 1; off < 16; off <<= 1) mm = fmaxf(mm, __shfl_xor(mm, off, 64));
    }
    float den = 0.f;
    for (int e = beg + eoff; e < end; e += ES) {
        int s = csr[e];
        float x = als[(size_t)s * H + h] + ad;
        x = (x > 0.f) ? x : 0.2f * x;
        den += __expf(x - mm);
    }
    if (H == 4) {
        den += __shfl_xor(den, 4, 64);
        den += __shfl_xor(den, 8, 64);
    } else {
#pragma unroll
        for (int off = 1; off < 16; off <<= 1) den += __shfl_xor(den, off, 64);
    }
    if (eoff == 0) {
        minv[(size_t)node * H + h] = mm;
        dinv[(size_t)node * H + h] = 1.f / (den + 1e-16f);
    }
}

// ---------------- GAT aggregation: one wave per destination node, single pass ----------------
template <int CHUNK, bool ELU, typename FT, typename OT>
__global__ void k_agg(const FT* __restrict__ feat, const int* __restrict__ offs,
                      const int* __restrict__ csr, const float* __restrict__ als,
                      const float* __restrict__ ald, const float* __restrict__ minv,
                      const float* __restrict__ dinv, const float* __restrict__ bias,
                      OT* __restrict__ out, int N) {
    constexpr int M = 64 * CHUNK;
    constexpr int H = M / 64;
    int lane = threadIdx.x & 63;
    int node = blockIdx.x * 4 + (threadIdx.x >> 6);
    if (node >= N) return;
    int head = (CHUNK == 4) ? (lane >> 4) : 0;
    float ad  = ald[(size_t)node * H + head];
    float m   = minv[(size_t)node * H + head];
    float inv = dinv[(size_t)node * H + head];
    int beg = offs[node], end = offs[node + 1];

    float acc[CHUNK] = {};
    int   s0 = csr[beg];
    float x0 = als[(size_t)s0 * H + head];
    float f0[CHUNK];
    ldrow<CHUNK>(feat + (size_t)s0 * M + lane * CHUNK, f0);
    for (int e = beg; e < end - 1; ++e) {
        int   s1 = csr[e + 1];
        float x1 = als[(size_t)s1 * H + head];
        float f1[CHUNK];
        ldrow<CHUNK>(feat + (size_t)s1 * M + lane * CHUNK, f1);
        float x = x0 + ad;
        x = (x > 0.f) ? x : 0.2f * x;
        float w = __expf(x - m);
#pragma unroll
        for (int j = 0; j < CHUNK; ++j) acc[j] = fmaf(w, f0[j], acc[j]);
        x0 = x1;
#pragma unroll
        for (int j = 0; j < CHUNK; ++j) f0[j] = f1[j];
    }
    {
        float x = x0 + ad;
        x = (x > 0.f) ? x : 0.2f * x;
        float w = __expf(x - m);
#pragma unroll
        for (int j = 0; j < CHUNK; ++j) acc[j] = fmaf(w, f0[j], acc[j]);
    }
#pragma unroll
    for (int j = 0; j < CHUNK; ++j) {
        int col = lane * CHUNK + j;
        float v = acc[j] * inv + bias[col];
        if (ELU) v = (v > 0.f) ? v : (__expf(v) - 1.f);
        st(&out[(size_t)node * M + col], v);
    }
}

// ---------------- global mean pool: batch sorted -> one block per graph ----------------
static __device__ __forceinline__ int lowerb(const int* __restrict__ a, int n, int v) {
    int lo = 0, hi = n;
    while (lo < hi) { int mid = (lo + hi) >> 1; if (a[mid] < v) lo = mid + 1; else hi = mid; }
    return lo;
}

__global__ void k_pool2(const float* __restrict__ ne, const int* __restrict__ batch,
                        float* __restrict__ gout, int N) {
    int g = blockIdx.x;
    int lo = lowerb(batch, N, g);
    int hi = lowerb(batch, N, g + 1);
    int lane = threadIdx.x & 63, row = threadIdx.x >> 6;
    float s = 0.f;
    for (int i = lo + row; i < hi; i += 4) s += ne[(size_t)i * 64 + lane];
    __shared__ float red[4][64];
    red[row][lane] = s;
    __syncthreads();
    if (row == 0) {
        float v = red[0][lane] + red[1][lane] + red[2][lane] + red[3][lane];
        gout[(size_t)g * 64 + lane] = v / fmaxf((float)(hi - lo), 1.f);
    }
}

extern "C" void kernel_launch(void* const* d_in, const int* in_sizes, int n_in,
                              void* d_out, int out_size, void* d_ws, size_t ws_size,
                              hipStream_t stream) {
    const float* x   = (const float*)d_in[0];
    const int* ei    = (const int*)d_in[1];
    const int* batch = (const int*)d_in[2];
    const float* W1  = (const float*)d_in[3];
    const float* as1 = (const float*)d_in[4];
    const float* ad1 = (const float*)d_in[5];
    const float* b1  = (const float*)d_in[6];
    const float* W2  = (const float*)d_in[7];
    const float* as2 = (const float*)d_in[8];
    const float* ad2 = (const float*)d_in[9];
    const float* b2  = (const float*)d_in[10];
    const float* W3  = (const float*)d_in[11];
    const float* as3 = (const float*)d_in[12];
    const float* ad3 = (const float*)d_in[13];
    const float* b3  = (const float*)d_in[14];

    const int N = in_sizes[2];      // 50000
    const int E = in_sizes[1] / 2;  // 800000
    const int G = 64;
    float* out = (float*)d_out;

    // workspace (~58 MB): f16 intermediates, fp32 scalars, CSR
    char* w = (char*)d_ws;
    auto carve = [&](size_t bytes) { char* p = w; w += (bytes + 255) & ~(size_t)255; return p; };
    __half* feat = (__half*)carve((size_t)N * 256 * 2);
    __half* act  = (__half*)carve((size_t)N * 256 * 2);
    float* als   = (float*)carve((size_t)N * 4 * 4);
    float* ald   = (float*)carve((size_t)N * 4 * 4);
    float* minv  = (float*)carve((size_t)N * 4 * 4);
    float* dinv  = (float*)carve((size_t)N * 4 * 4);
    int* deg     = (int*)carve((size_t)N * 4);
    int* offs    = (int*)carve((size_t)(N + 1) * 4);
    int* cursor  = (int*)carve((size_t)N * 4);
    int* csr     = (int*)carve((size_t)(E + N) * 4);

    k_init<<<(N + 255) / 256, 256, 0, stream>>>(deg, N);
    k_hist<<<(E + 255) / 256, 256, 0, stream>>>(ei, deg, E);
    k_scan<<<1, 1024, 0, stream>>>(deg, offs, cursor, N);
    k_scatter<<<(E + 255) / 256, 256, 0, stream>>>(ei, cursor, csr, E);
    k_scatter_loops<<<(N + 255) / 256, 256, 0, stream>>>(cursor, csr, N);

    dim3 gemmBig((N + 127) / 128, 4);    // M=256, BN=64
    dim3 gemmSmall((N + 127) / 128, 1);  // M=64
    int nodeBlocks = (N + 3) / 4;
    int mdBlocks   = (N + 15) / 16;

    // layer 1: x(fp32) @ W1 -> feat(f16); attention; aggregate+bias+ELU -> act(f16)
    k_gemm_mfma<float><<<gemmBig, 256, 0, stream>>>(x, W1, feat, N, 256, 256);
    k_alpha<4, __half><<<nodeBlocks, 256, 0, stream>>>(feat, as1, ad1, als, ald, N);
    k_maxden<4><<<mdBlocks, 256, 0, stream>>>(offs, csr, als, ald, minv, dinv, N);
    k_agg<4, true, __half, __half><<<nodeBlocks, 256, 0, stream>>>(feat, offs, csr, als, ald, minv, dinv, b1, act, N);
    // layer 2
    k_gemm_mfma<__half><<<gemmBig, 256, 0, stream>>>(act, W2, feat, N, 256, 256);
    k_alpha<4, __half><<<nodeBlocks, 256, 0, stream>>>(feat, as2, ad2, als, ald, N);
    k_maxden<4><<<mdBlocks, 256, 0, stream>>>(offs, csr, als, ald, minv, dinv, N);
    k_agg<4, true, __half, __half><<<nodeBlocks, 256, 0, stream>>>(feat, offs, csr, als, ald, minv, dinv, b2, act, N);
    // layer 3: 256 -> 64, single head, no ELU; fp32 node embeddings straight to d_out
    k_gemm_mfma<__half><<<gemmSmall, 256, 0, stream>>>(act, W3, feat, N, 256, 64);
    k_alpha<1, __half><<<nodeBlocks, 256, 0, stream>>>(feat, as3, ad3, als, ald, N);
    k_maxden<1><<<mdBlocks, 256, 0, stream>>>(offs, csr, als, ald, minv, dinv, N);
    k_agg<1, false, __half, float><<<nodeBlocks, 256, 0, stream>>>(feat, offs, csr, als, ald, minv, dinv, b3, out, N);

    // global mean pool
    k_pool2<<<G, 256, 0, stream>>>(out, batch, out + (size_t)N * 64, N);
}

// Round 8
// 759.417 us; speedup vs baseline: 2.2178x; 1.1301x over previous
//
#include <hip/hip_runtime.h>
#include <hip/hip_bf16.h>
#include <hip/hip_fp16.h>

typedef __attribute__((ext_vector_type(8))) short bf16x8;
typedef __attribute__((ext_vector_type(4))) float f32x4;

static __device__ __forceinline__ float ld(const float* p)  { return *p; }
static __device__ __forceinline__ float ld(const __half* p) { return __half2float(*p); }
static __device__ __forceinline__ void st(float* p, float v)  { *p = v; }
static __device__ __forceinline__ void st(__half* p, float v) { *p = __float2half(v); }

// fp32 -> bf16 RNE on raw bits
static __device__ __forceinline__ unsigned short f2bf(float f) {
    unsigned int u = __builtin_bit_cast(unsigned int, f);
    unsigned int r = u + 0x7FFFu + ((u >> 16) & 1u);
    return (unsigned short)(r >> 16);
}
static __device__ __forceinline__ float bf2f(unsigned short h) {
    unsigned int u = ((unsigned int)h) << 16;
    return __builtin_bit_cast(float, u);
}
static __device__ __forceinline__ void split(float v, unsigned short& hi, unsigned short& lo) {
    hi = f2bf(v);
    lo = f2bf(v - bf2f(hi));
}

// vectorized row loaders (CHUNK consecutive channels per lane)
static __device__ __forceinline__ void ldrow4(const float* p, float* f) {
    float4 v = *reinterpret_cast<const float4*>(p);
    f[0] = v.x; f[1] = v.y; f[2] = v.z; f[3] = v.w;
}
static __device__ __forceinline__ void ldrow4(const __half* p, float* f) {
    const __half2* q = reinterpret_cast<const __half2*>(p);
    float2 a = __half22float2(q[0]), b = __half22float2(q[1]);
    f[0] = a.x; f[1] = a.y; f[2] = b.x; f[3] = b.y;
}
static __device__ __forceinline__ void ldrow1(const float* p, float* f)  { f[0] = *p; }
static __device__ __forceinline__ void ldrow1(const __half* p, float* f) { f[0] = __half2float(*p); }
template <int CHUNK, typename FT>
static __device__ __forceinline__ void ldrow(const FT* p, float* f) {
    if constexpr (CHUNK == 4) ldrow4(p, f); else ldrow1(p, f);
}

// ---------------- CSR build ----------------
__global__ void k_init(int* deg, int N) {
    int i = blockIdx.x * blockDim.x + threadIdx.x;
    if (i < N) deg[i] = 1;              // self-loop
}

__global__ void k_hist(const int* __restrict__ ei, int* deg, int E) {
    int e = blockIdx.x * blockDim.x + threadIdx.x;
    if (e < E) atomicAdd(&deg[ei[E + e]], 1);
}

// hierarchical exclusive scan: 3 tiny parallel kernels (replaces 111us mono-block scan)
__global__ void k_scan1(const int* __restrict__ deg, int* __restrict__ offs,
                        int* __restrict__ bsum, int N) {
    __shared__ int sh[256];
    int i = blockIdx.x * 256 + threadIdx.x;
    int v = (i < N) ? deg[i] : 0;
    sh[threadIdx.x] = v;
    __syncthreads();
#pragma unroll
    for (int off = 1; off < 256; off <<= 1) {
        int t = (threadIdx.x >= off) ? sh[threadIdx.x - off] : 0;
        __syncthreads();
        sh[threadIdx.x] += t;
        __syncthreads();
    }
    if (i < N) offs[i] = sh[threadIdx.x] - v;          // exclusive within block
    if (threadIdx.x == 255) bsum[blockIdx.x] = sh[255]; // block total
}

__global__ void k_scan2(int* __restrict__ bsum, int nb) {   // nb <= 256, single block
    __shared__ int sh[256];
    int v = (threadIdx.x < nb) ? bsum[threadIdx.x] : 0;
    sh[threadIdx.x] = v;
    __syncthreads();
#pragma unroll
    for (int off = 1; off < 256; off <<= 1) {
        int t = (threadIdx.x >= off) ? sh[threadIdx.x - off] : 0;
        __syncthreads();
        sh[threadIdx.x] += t;
        __syncthreads();
    }
    if (threadIdx.x < nb) bsum[threadIdx.x] = sh[threadIdx.x] - v;  // exclusive
    if (threadIdx.x == 255) bsum[nb] = sh[255];                     // grand total
}

__global__ void k_scan3(int* __restrict__ offs, int* __restrict__ cursor,
                        const int* __restrict__ bsum, int N, int nb) {
    int i = blockIdx.x * 256 + threadIdx.x;
    if (i < N) {
        int v = offs[i] + bsum[blockIdx.x];
        offs[i] = v;
        cursor[i] = v;
    }
    if (i == 0) offs[N] = bsum[nb];
}

__global__ void k_scatter(const int* __restrict__ ei, int* cursor, int* csr, int E) {
    int e = blockIdx.x * blockDim.x + threadIdx.x;
    if (e < E) {
        int d = ei[E + e];
        int p = atomicAdd(&cursor[d], 1);
        csr[p] = ei[e];
    }
}

__global__ void k_scatter_loops(int* cursor, int* csr, int N) {
    int i = blockIdx.x * blockDim.x + threadIdx.x;
    if (i < N) { int p = atomicAdd(&cursor[i], 1); csr[p] = i; }
}

// ---------------- split-bf16 MFMA GEMM ----------------
// C[nrows,M](f16) = A[nrows,K] @ W[K,M](fp32), via A=Ah+Al, B=Bh+Bl (bf16):
// D += Ah*Bh + Ah*Bl + Al*Bh  (lo*lo term ~2^-16, dropped).
// BM=128, BN=64, BK=64; 256 threads = 4 waves in 2x2; wave tile 64x32 = 4x2 MFMA tiles.
template <typename AT>
__global__ __launch_bounds__(256) void k_gemm_mfma(const AT* __restrict__ A, const float* __restrict__ W,
                                                   __half* __restrict__ C, int nrows, int K, int M) {
    constexpr int LDA = 72;   // row stride (shorts), 144B = 16B-aligned, breaks stride-128 conflicts
    __shared__ unsigned short AH[128 * LDA];
    __shared__ unsigned short AL[128 * LDA];
    __shared__ unsigned short BH[64 * LDA];   // stored transposed: [n][k]
    __shared__ unsigned short BL[64 * LDA];

    int tid  = threadIdx.x;
    int lane = tid & 63;
    int wave = tid >> 6;
    int wr = wave & 1, wc = wave >> 1;        // wave grid 2x2
    int quad = lane >> 4, r = lane & 15;
    int r0 = blockIdx.x * 128, c0 = blockIdx.y * 64;

    f32x4 acc[4][2];
#pragma unroll
    for (int i = 0; i < 4; ++i)
#pragma unroll
        for (int j = 0; j < 2; ++j) acc[i][j] = (f32x4){0.f, 0.f, 0.f, 0.f};

    for (int kc = 0; kc < K; kc += 64) {
        // ---- stage A: 128 rows x 64 k, split to hi/lo ----
#pragma unroll
        for (int it = 0; it < 4; ++it) {
            int row  = (tid >> 3) + it * 32;
            int kseg = (tid & 7) * 8;
            int gr = r0 + row;
            unsigned short h[8], l[8];
            if (gr < nrows) {
                const AT* src = A + (size_t)gr * K + kc + kseg;
#pragma unroll
                for (int j = 0; j < 8; ++j) split(ld(src + j), h[j], l[j]);
            } else {
#pragma unroll
                for (int j = 0; j < 8; ++j) { h[j] = 0; l[j] = 0; }
            }
            *reinterpret_cast<bf16x8*>(&AH[row * LDA + kseg]) = *reinterpret_cast<bf16x8*>(h);
            *reinterpret_cast<bf16x8*>(&AL[row * LDA + kseg]) = *reinterpret_cast<bf16x8*>(l);
        }
        // ---- stage B: 64 k x 64 n from W (row-major), transposed into [n][k] ----
#pragma unroll
        for (int it = 0; it < 4; ++it) {
            int kk = (tid >> 4) + it * 16;
            int n4 = (tid & 15) * 4;
            float4 v = *reinterpret_cast<const float4*>(W + (size_t)(kc + kk) * M + c0 + n4);
            float f[4] = {v.x, v.y, v.z, v.w};
#pragma unroll
            for (int j = 0; j < 4; ++j) {
                unsigned short h, l;
                split(f[j], h, l);
                BH[(n4 + j) * LDA + kk] = h;
                BL[(n4 + j) * LDA + kk] = l;
            }
        }
        __syncthreads();
        // ---- compute: two 16x16x32 k-steps ----
#pragma unroll
        for (int ks = 0; ks < 2; ++ks) {
            int k0 = ks * 32 + quad * 8;
            bf16x8 ah[4], al[4], bh[2], bl[2];
#pragma unroll
            for (int tr = 0; tr < 4; ++tr) {
                int row = wr * 64 + tr * 16 + r;
                ah[tr] = *reinterpret_cast<const bf16x8*>(&AH[row * LDA + k0]);
                al[tr] = *reinterpret_cast<const bf16x8*>(&AL[row * LDA + k0]);
            }
#pragma unroll
            for (int tc = 0; tc < 2; ++tc) {
                int col = wc * 32 + tc * 16 + r;
                bh[tc] = *reinterpret_cast<const bf16x8*>(&BH[col * LDA + k0]);
                bl[tc] = *reinterpret_cast<const bf16x8*>(&BL[col * LDA + k0]);
            }
#pragma unroll
            for (int tr = 0; tr < 4; ++tr)
#pragma unroll
                for (int tc = 0; tc < 2; ++tc) {
                    acc[tr][tc] = __builtin_amdgcn_mfma_f32_16x16x32_bf16(ah[tr], bh[tc], acc[tr][tc], 0, 0, 0);
                    acc[tr][tc] = __builtin_amdgcn_mfma_f32_16x16x32_bf16(ah[tr], bl[tc], acc[tr][tc], 0, 0, 0);
                    acc[tr][tc] = __builtin_amdgcn_mfma_f32_16x16x32_bf16(al[tr], bh[tc], acc[tr][tc], 0, 0, 0);
                }
        }
        __syncthreads();
    }
    // ---- epilogue: D lane mapping col=lane&15, row=quad*4+reg ----
#pragma unroll
    for (int tr = 0; tr < 4; ++tr)
#pragma unroll
        for (int tc = 0; tc < 2; ++tc) {
            int col = c0 + wc * 32 + tc * 16 + r;
#pragma unroll
            for (int i = 0; i < 4; ++i) {
                int row = r0 + wr * 64 + tr * 16 + quad * 4 + i;
                if (row < nrows) C[(size_t)row * M + col] = __float2half(acc[tr][tc][i]);
            }
        }
}

// ---------------- attention coefficients ----------------
template <int CHUNK, typename FT>
__global__ void k_alpha(const FT* __restrict__ feat, const float* __restrict__ a_src,
                        const float* __restrict__ a_dst, float* __restrict__ als,
                        float* __restrict__ ald, int N) {
    constexpr int M = 64 * CHUNK;
    constexpr int H = M / 64;
    constexpr int WIDTH = 64 / H;
    int lane = threadIdx.x & 63;
    int node = blockIdx.x * 4 + (threadIdx.x >> 6);
    if (node >= N) return;
    float f[CHUNK];
    ldrow<CHUNK>(feat + (size_t)node * M + lane * CHUNK, f);
    float ps = 0.f, pd = 0.f;
#pragma unroll
    for (int j = 0; j < CHUNK; ++j) {
        int col = lane * CHUNK + j;
        ps += f[j] * a_src[col];
        pd += f[j] * a_dst[col];
    }
#pragma unroll
    for (int off = 1; off < WIDTH; off <<= 1) {
        ps += __shfl_xor(ps, off, 64);
        pd += __shfl_xor(pd, off, 64);
    }
    if ((lane & (WIDTH - 1)) == 0) {
        int head = lane / WIDTH;
        als[(size_t)node * H + head] = ps;
        ald[(size_t)node * H + head] = pd;
    }
}

// ---------------- segment max + denominator ----------------
template <int H>
__global__ void k_maxden(const int* __restrict__ offs, const int* __restrict__ csr,
                         const float* __restrict__ als, const float* __restrict__ ald,
                         float* __restrict__ minv, float* __restrict__ dinv, int N) {
    int sub  = threadIdx.x & 15;
    int node = blockIdx.x * 16 + (threadIdx.x >> 4);
    if (node >= N) return;
    constexpr int ES = (H == 4) ? 4 : 16;
    int h    = (H == 4) ? (sub & 3) : 0;
    int eoff = (H == 4) ? (sub >> 2) : sub;
    float ad = ald[(size_t)node * H + h];
    int beg = offs[node], end = offs[node + 1];

    float mm = -1e30f;
    for (int e = beg + eoff; e < end; e += ES) {
        int s = csr[e];
        float x = als[(size_t)s * H + h] + ad;
        x = (x > 0.f) ? x : 0.2f * x;
        mm = fmaxf(mm, x);
    }
    if (H == 4) {
        mm = fmaxf(mm, __shfl_xor(mm, 4, 64));
        mm = fmaxf(mm, __shfl_xor(mm, 8, 64));
    } else {
#pragma unroll
        for (int off = 1; off < 16; off <<= 1) mm = fmaxf(mm, __shfl_xor(mm, off, 64));
    }
    float den = 0.f;
    for (int e = beg + eoff; e < end; e += ES) {
        int s = csr[e];
        float x = als[(size_t)s * H + h] + ad;
        x = (x > 0.f) ? x : 0.2f * x;
        den += __expf(x - mm);
    }
    if (H == 4) {
        den += __shfl_xor(den, 4, 64);
        den += __shfl_xor(den, 8, 64);
    } else {
#pragma unroll
        for (int off = 1; off < 16; off <<= 1) den += __shfl_xor(den, off, 64);
    }
    if (eoff == 0) {
        minv[(size_t)node * H + h] = mm;
        dinv[(size_t)node * H + h] = 1.f / (den + 1e-16f);
    }
}

// ---------------- GAT aggregation: one wave per destination node, single pass ----------------
template <int CHUNK, bool ELU, typename FT, typename OT>
__global__ void k_agg(const FT* __restrict__ feat, const int* __restrict__ offs,
                      const int* __restrict__ csr, const float* __restrict__ als,
                      const float* __restrict__ ald, const float* __restrict__ minv,
                      const float* __restrict__ dinv, const float* __restrict__ bias,
                      OT* __restrict__ out, int N) {
    constexpr int M = 64 * CHUNK;
    constexpr int H = M / 64;
    int lane = threadIdx.x & 63;
    int node = blockIdx.x * 4 + (threadIdx.x >> 6);
    if (node >= N) return;
    int head = (CHUNK == 4) ? (lane >> 4) : 0;
    float ad  = ald[(size_t)node * H + head];
    float m   = minv[(size_t)node * H + head];
    float inv = dinv[(size_t)node * H + head];
    int beg = offs[node], end = offs[node + 1];

    float acc[CHUNK] = {};
    int   s0 = csr[beg];
    float x0 = als[(size_t)s0 * H + head];
    float f0[CHUNK];
    ldrow<CHUNK>(feat + (size_t)s0 * M + lane * CHUNK, f0);
    for (int e = beg; e < end - 1; ++e) {
        int   s1 = csr[e + 1];
        float x1 = als[(size_t)s1 * H + head];
        float f1[CHUNK];
        ldrow<CHUNK>(feat + (size_t)s1 * M + lane * CHUNK, f1);
        float x = x0 + ad;
        x = (x > 0.f) ? x : 0.2f * x;
        float w = __expf(x - m);
#pragma unroll
        for (int j = 0; j < CHUNK; ++j) acc[j] = fmaf(w, f0[j], acc[j]);
        x0 = x1;
#pragma unroll
        for (int j = 0; j < CHUNK; ++j) f0[j] = f1[j];
    }
    {
        float x = x0 + ad;
        x = (x > 0.f) ? x : 0.2f * x;
        float w = __expf(x - m);
#pragma unroll
        for (int j = 0; j < CHUNK; ++j) acc[j] = fmaf(w, f0[j], acc[j]);
    }
#pragma unroll
    for (int j = 0; j < CHUNK; ++j) {
        int col = lane * CHUNK + j;
        float v = acc[j] * inv + bias[col];
        if (ELU) v = (v > 0.f) ? v : (__expf(v) - 1.f);
        st(&out[(size_t)node * M + col], v);
    }
}

// ---------------- global mean pool: batch sorted -> one block per graph ----------------
static __device__ __forceinline__ int lowerb(const int* __restrict__ a, int n, int v) {
    int lo = 0, hi = n;
    while (lo < hi) { int mid = (lo + hi) >> 1; if (a[mid] < v) lo = mid + 1; else hi = mid; }
    return lo;
}

__global__ void k_pool2(const float* __restrict__ ne, const int* __restrict__ batch,
                        float* __restrict__ gout, int N) {
    int g = blockIdx.x;
    int lo = lowerb(batch, N, g);
    int hi = lowerb(batch, N, g + 1);
    int lane = threadIdx.x & 63, row = threadIdx.x >> 6;
    float s = 0.f;
    for (int i = lo + row; i < hi; i += 4) s += ne[(size_t)i * 64 + lane];
    __shared__ float red[4][64];
    red[row][lane] = s;
    __syncthreads();
    if (row == 0) {
        float v = red[0][lane] + red[1][lane] + red[2][lane] + red[3][lane];
        gout[(size_t)g * 64 + lane] = v / fmaxf((float)(hi - lo), 1.f);
    }
}

extern "C" void kernel_launch(void* const* d_in, const int* in_sizes, int n_in,
                              void* d_out, int out_size, void* d_ws, size_t ws_size,
                              hipStream_t stream) {
    const float* x   = (const float*)d_in[0];
    const int* ei    = (const int*)d_in[1];
    const int* batch = (const int*)d_in[2];
    const float* W1  = (const float*)d_in[3];
    const float* as1 = (const float*)d_in[4];
    const float* ad1 = (const float*)d_in[5];
    const float* b1  = (const float*)d_in[6];
    const float* W2  = (const float*)d_in[7];
    const float* as2 = (const float*)d_in[8];
    const float* ad2 = (const float*)d_in[9];
    const float* b2  = (const float*)d_in[10];
    const float* W3  = (const float*)d_in[11];
    const float* as3 = (const float*)d_in[12];
    const float* ad3 = (const float*)d_in[13];
    const float* b3  = (const float*)d_in[14];

    const int N = in_sizes[2];      // 50000
    const int E = in_sizes[1] / 2;  // 800000
    const int G = 64;
    float* out = (float*)d_out;

    // workspace (~58 MB): f16 intermediates, fp32 scalars, CSR
    char* w = (char*)d_ws;
    auto carve = [&](size_t bytes) { char* p = w; w += (bytes + 255) & ~(size_t)255; return p; };
    __half* feat = (__half*)carve((size_t)N * 256 * 2);
    __half* act  = (__half*)carve((size_t)N * 256 * 2);
    float* als   = (float*)carve((size_t)N * 4 * 4);
    float* ald   = (float*)carve((size_t)N * 4 * 4);
    float* minv  = (float*)carve((size_t)N * 4 * 4);
    float* dinv  = (float*)carve((size_t)N * 4 * 4);
    int* deg     = (int*)carve((size_t)N * 4);
    int* offs    = (int*)carve((size_t)(N + 1) * 4);
    int* cursor  = (int*)carve((size_t)N * 4);
    int* csr     = (int*)carve((size_t)(E + N) * 4);
    int nb       = (N + 255) / 256;
    int* bsum    = (int*)carve((size_t)(nb + 1) * 4);

    k_init<<<(N + 255) / 256, 256, 0, stream>>>(deg, N);
    k_hist<<<(E + 255) / 256, 256, 0, stream>>>(ei, deg, E);
    k_scan1<<<nb, 256, 0, stream>>>(deg, offs, bsum, N);
    k_scan2<<<1, 256, 0, stream>>>(bsum, nb);
    k_scan3<<<nb, 256, 0, stream>>>(offs, cursor, bsum, N, nb);
    k_scatter<<<(E + 255) / 256, 256, 0, stream>>>(ei, cursor, csr, E);
    k_scatter_loops<<<(N + 255) / 256, 256, 0, stream>>>(cursor, csr, N);

    dim3 gemmBig((N + 127) / 128, 4);    // M=256, BN=64
    dim3 gemmSmall((N + 127) / 128, 1);  // M=64
    int nodeBlocks = (N + 3) / 4;
    int mdBlocks   = (N + 15) / 16;

    // layer 1: x(fp32) @ W1 -> feat(f16); attention; aggregate+bias+ELU -> act(f16)
    k_gemm_mfma<float><<<gemmBig, 256, 0, stream>>>(x, W1, feat, N, 256, 256);
    k_alpha<4, __half><<<nodeBlocks, 256, 0, stream>>>(feat, as1, ad1, als, ald, N);
    k_maxden<4><<<mdBlocks, 256, 0, stream>>>(offs, csr, als, ald, minv, dinv, N);
    k_agg<4, true, __half, __half><<<nodeBlocks, 256, 0, stream>>>(feat, offs, csr, als, ald, minv, dinv, b1, act, N);
    // layer 2
    k_gemm_mfma<__half><<<gemmBig, 256, 0, stream>>>(act, W2, feat, N, 256, 256);
    k_alpha<4, __half><<<nodeBlocks, 256, 0, stream>>>(feat, as2, ad2, als, ald, N);
    k_maxden<4><<<mdBlocks, 256, 0, stream>>>(offs, csr, als, ald, minv, dinv, N);
    k_agg<4, true, __half, __half><<<nodeBlocks, 256, 0, stream>>>(feat, offs, csr, als, ald, minv, dinv, b2, act, N);
    // layer 3: 256 -> 64, single head, no ELU; fp32 node embeddings straight to d_out
    k_gemm_mfma<__half><<<gemmSmall, 256, 0, stream>>>(act, W3, feat, N, 256, 64);
    k_alpha<1, __half><<<nodeBlocks, 256, 0, stream>>>(feat, as3, ad3, als, ald, N);
    k_maxden<1><<<mdBlocks, 256, 0, stream>>>(offs, csr, als, ald, minv, dinv, N);
    k_agg<1, false, __half, float><<<nodeBlocks, 256, 0, stream>>>(feat, offs, csr, als, ald, minv, dinv, b3, out, N);

    // global mean pool
    k_pool2<<<G, 256, 0, stream>>>(out, batch, out + (size_t)N * 64, N);
}

// Round 9
// 680.478 us; speedup vs baseline: 2.4751x; 1.1160x over previous
//
#include <hip/hip_runtime.h>
#include <hip/hip_bf16.h>
#include <hip/hip_fp16.h>

typedef __attribute__((ext_vector_type(8))) short bf16x8;
typedef __attribute__((ext_vector_type(4))) float f32x4;

static __device__ __forceinline__ float ld(const float* p)  { return *p; }
static __device__ __forceinline__ float ld(const __half* p) { return __half2float(*p); }
static __device__ __forceinline__ void st(float* p, float v)  { *p = v; }
static __device__ __forceinline__ void st(__half* p, float v) { *p = __float2half(v); }

// fp32 -> bf16 RNE on raw bits
static __device__ __forceinline__ unsigned short f2bf(float f) {
    unsigned int u = __builtin_bit_cast(unsigned int, f);
    unsigned int r = u + 0x7FFFu + ((u >> 16) & 1u);
    return (unsigned short)(r >> 16);
}
static __device__ __forceinline__ float bf2f(unsigned short h) {
    unsigned int u = ((unsigned int)h) << 16;
    return __builtin_bit_cast(float, u);
}
static __device__ __forceinline__ void split(float v, unsigned short& hi, unsigned short& lo) {
    hi = f2bf(v);
    lo = f2bf(v - bf2f(hi));
}

// vectorized row loaders (CHUNK consecutive channels per lane)
static __device__ __forceinline__ void ldrow4(const float* p, float* f) {
    float4 v = *reinterpret_cast<const float4*>(p);
    f[0] = v.x; f[1] = v.y; f[2] = v.z; f[3] = v.w;
}
static __device__ __forceinline__ void ldrow4(const __half* p, float* f) {
    const __half2* q = reinterpret_cast<const __half2*>(p);
    float2 a = __half22float2(q[0]), b = __half22float2(q[1]);
    f[0] = a.x; f[1] = a.y; f[2] = b.x; f[3] = b.y;
}
static __device__ __forceinline__ void ldrow1(const float* p, float* f)  { f[0] = *p; }
static __device__ __forceinline__ void ldrow1(const __half* p, float* f) { f[0] = __half2float(*p); }
template <int CHUNK, typename FT>
static __device__ __forceinline__ void ldrow(const FT* p, float* f) {
    if constexpr (CHUNK == 4) ldrow4(p, f); else ldrow1(p, f);
}

// ---------------- CSR build ----------------
__global__ void k_init(int* deg, int N) {
    int i = blockIdx.x * blockDim.x + threadIdx.x;
    if (i < N) deg[i] = 1;              // self-loop
}

__global__ void k_hist(const int* __restrict__ ei, int* deg, int E) {
    int e = blockIdx.x * blockDim.x + threadIdx.x;
    if (e < E) atomicAdd(&deg[ei[E + e]], 1);
}

// hierarchical exclusive scan
__global__ void k_scan1(const int* __restrict__ deg, int* __restrict__ offs,
                        int* __restrict__ bsum, int N) {
    __shared__ int sh[256];
    int i = blockIdx.x * 256 + threadIdx.x;
    int v = (i < N) ? deg[i] : 0;
    sh[threadIdx.x] = v;
    __syncthreads();
#pragma unroll
    for (int off = 1; off < 256; off <<= 1) {
        int t = (threadIdx.x >= off) ? sh[threadIdx.x - off] : 0;
        __syncthreads();
        sh[threadIdx.x] += t;
        __syncthreads();
    }
    if (i < N) offs[i] = sh[threadIdx.x] - v;
    if (threadIdx.x == 255) bsum[blockIdx.x] = sh[255];
}

__global__ void k_scan2(int* __restrict__ bsum, int nb) {   // nb <= 256, single block
    __shared__ int sh[256];
    int v = (threadIdx.x < nb) ? bsum[threadIdx.x] : 0;
    sh[threadIdx.x] = v;
    __syncthreads();
#pragma unroll
    for (int off = 1; off < 256; off <<= 1) {
        int t = (threadIdx.x >= off) ? sh[threadIdx.x - off] : 0;
        __syncthreads();
        sh[threadIdx.x] += t;
        __syncthreads();
    }
    if (threadIdx.x < nb) bsum[threadIdx.x] = sh[threadIdx.x] - v;
    if (threadIdx.x == 255) bsum[nb] = sh[255];
}

__global__ void k_scan3(int* __restrict__ offs, int* __restrict__ cursor,
                        const int* __restrict__ bsum, int N, int nb) {
    int i = blockIdx.x * 256 + threadIdx.x;
    if (i < N) {
        int v = offs[i] + bsum[blockIdx.x];
        offs[i] = v;
        cursor[i] = v;
    }
    if (i == 0) offs[N] = bsum[nb];
}

__global__ void k_scatter(const int* __restrict__ ei, int* cursor, int* csr, int E) {
    int e = blockIdx.x * blockDim.x + threadIdx.x;
    if (e < E) {
        int d = ei[E + e];
        int p = atomicAdd(&cursor[d], 1);
        csr[p] = ei[e];
    }
}

__global__ void k_scatter_loops(int* cursor, int* csr, int N) {
    int i = blockIdx.x * blockDim.x + threadIdx.x;
    if (i < N) { int p = atomicAdd(&cursor[i], 1); csr[p] = i; }
}

// ---------------- split-bf16 MFMA GEMM ----------------
template <typename AT>
__global__ __launch_bounds__(256) void k_gemm_mfma(const AT* __restrict__ A, const float* __restrict__ W,
                                                   __half* __restrict__ C, int nrows, int K, int M) {
    constexpr int LDA = 72;
    __shared__ unsigned short AH[128 * LDA];
    __shared__ unsigned short AL[128 * LDA];
    __shared__ unsigned short BH[64 * LDA];
    __shared__ unsigned short BL[64 * LDA];

    int tid  = threadIdx.x;
    int lane = tid & 63;
    int wave = tid >> 6;
    int wr = wave & 1, wc = wave >> 1;
    int quad = lane >> 4, r = lane & 15;
    int r0 = blockIdx.x * 128, c0 = blockIdx.y * 64;

    f32x4 acc[4][2];
#pragma unroll
    for (int i = 0; i < 4; ++i)
#pragma unroll
        for (int j = 0; j < 2; ++j) acc[i][j] = (f32x4){0.f, 0.f, 0.f, 0.f};

    for (int kc = 0; kc < K; kc += 64) {
#pragma unroll
        for (int it = 0; it < 4; ++it) {
            int row  = (tid >> 3) + it * 32;
            int kseg = (tid & 7) * 8;
            int gr = r0 + row;
            unsigned short h[8], l[8];
            if (gr < nrows) {
                const AT* src = A + (size_t)gr * K + kc + kseg;
#pragma unroll
                for (int j = 0; j < 8; ++j) split(ld(src + j), h[j], l[j]);
            } else {
#pragma unroll
                for (int j = 0; j < 8; ++j) { h[j] = 0; l[j] = 0; }
            }
            *reinterpret_cast<bf16x8*>(&AH[row * LDA + kseg]) = *reinterpret_cast<bf16x8*>(h);
            *reinterpret_cast<bf16x8*>(&AL[row * LDA + kseg]) = *reinterpret_cast<bf16x8*>(l);
        }
#pragma unroll
        for (int it = 0; it < 4; ++it) {
            int kk = (tid >> 4) + it * 16;
            int n4 = (tid & 15) * 4;
            float4 v = *reinterpret_cast<const float4*>(W + (size_t)(kc + kk) * M + c0 + n4);
            float f[4] = {v.x, v.y, v.z, v.w};
#pragma unroll
            for (int j = 0; j < 4; ++j) {
                unsigned short h, l;
                split(f[j], h, l);
                BH[(n4 + j) * LDA + kk] = h;
                BL[(n4 + j) * LDA + kk] = l;
            }
        }
        __syncthreads();
#pragma unroll
        for (int ks = 0; ks < 2; ++ks) {
            int k0 = ks * 32 + quad * 8;
            bf16x8 ah[4], al[4], bh[2], bl[2];
#pragma unroll
            for (int tr = 0; tr < 4; ++tr) {
                int row = wr * 64 + tr * 16 + r;
                ah[tr] = *reinterpret_cast<const bf16x8*>(&AH[row * LDA + k0]);
                al[tr] = *reinterpret_cast<const bf16x8*>(&AL[row * LDA + k0]);
            }
#pragma unroll
            for (int tc = 0; tc < 2; ++tc) {
                int col = wc * 32 + tc * 16 + r;
                bh[tc] = *reinterpret_cast<const bf16x8*>(&BH[col * LDA + k0]);
                bl[tc] = *reinterpret_cast<const bf16x8*>(&BL[col * LDA + k0]);
            }
#pragma unroll
            for (int tr = 0; tr < 4; ++tr)
#pragma unroll
                for (int tc = 0; tc < 2; ++tc) {
                    acc[tr][tc] = __builtin_amdgcn_mfma_f32_16x16x32_bf16(ah[tr], bh[tc], acc[tr][tc], 0, 0, 0);
                    acc[tr][tc] = __builtin_amdgcn_mfma_f32_16x16x32_bf16(ah[tr], bl[tc], acc[tr][tc], 0, 0, 0);
                    acc[tr][tc] = __builtin_amdgcn_mfma_f32_16x16x32_bf16(al[tr], bh[tc], acc[tr][tc], 0, 0, 0);
                }
        }
        __syncthreads();
    }
#pragma unroll
    for (int tr = 0; tr < 4; ++tr)
#pragma unroll
        for (int tc = 0; tc < 2; ++tc) {
            int col = c0 + wc * 32 + tc * 16 + r;
#pragma unroll
            for (int i = 0; i < 4; ++i) {
                int row = r0 + wr * 64 + tr * 16 + quad * 4 + i;
                if (row < nrows) C[(size_t)row * M + col] = __float2half(acc[tr][tc][i]);
            }
        }
}

// ---------------- attention coefficients ----------------
template <int CHUNK, typename FT>
__global__ void k_alpha(const FT* __restrict__ feat, const float* __restrict__ a_src,
                        const float* __restrict__ a_dst, float* __restrict__ als,
                        float* __restrict__ ald, int N) {
    constexpr int M = 64 * CHUNK;
    constexpr int H = M / 64;
    constexpr int WIDTH = 64 / H;
    int lane = threadIdx.x & 63;
    int node = blockIdx.x * 4 + (threadIdx.x >> 6);
    if (node >= N) return;
    float f[CHUNK];
    ldrow<CHUNK>(feat + (size_t)node * M + lane * CHUNK, f);
    float ps = 0.f, pd = 0.f;
#pragma unroll
    for (int j = 0; j < CHUNK; ++j) {
        int col = lane * CHUNK + j;
        ps += f[j] * a_src[col];
        pd += f[j] * a_dst[col];
    }
#pragma unroll
    for (int off = 1; off < WIDTH; off <<= 1) {
        ps += __shfl_xor(ps, off, 64);
        pd += __shfl_xor(pd, off, 64);
    }
    if ((lane & (WIDTH - 1)) == 0) {
        int head = lane / WIDTH;
        als[(size_t)node * H + head] = ps;
        ald[(size_t)node * H + head] = pd;
    }
}

// ---------------- segment max + denominator ----------------
template <int H>
__global__ void k_maxden(const int* __restrict__ offs, const int* __restrict__ csr,
                         const float* __restrict__ als, const float* __restrict__ ald,
                         float* __restrict__ minv, float* __restrict__ dinv, int N) {
    int sub  = threadIdx.x & 15;
    int node = blockIdx.x * 16 + (threadIdx.x >> 4);
    if (node >= N) return;
    constexpr int ES = (H == 4) ? 4 : 16;
    int h    = (H == 4) ? (sub & 3) : 0;
    int eoff = (H == 4) ? (sub >> 2) : sub;
    float ad = ald[(size_t)node * H + h];
    int beg = offs[node], end = offs[node + 1];

    float mm = -1e30f;
    for (int e = beg + eoff; e < end; e += ES) {
        int s = csr[e];
        float x = als[(size_t)s * H + h] + ad;
        x = (x > 0.f) ? x : 0.2f * x;
        mm = fmaxf(mm, x);
    }
    if (H == 4) {
        mm = fmaxf(mm, __shfl_xor(mm, 4, 64));
        mm = fmaxf(mm, __shfl_xor(mm, 8, 64));
    } else {
#pragma unroll
        for (int off = 1; off < 16; off <<= 1) mm = fmaxf(mm, __shfl_xor(mm, off, 64));
    }
    float den = 0.f;
    for (int e = beg + eoff; e < end; e += ES) {
        int s = csr[e];
        float x = als[(size_t)s * H + h] + ad;
        x = (x > 0.f) ? x : 0.2f * x;
        den += __expf(x - mm);
    }
    if (H == 4) {
        den += __shfl_xor(den, 4, 64);
        den += __shfl_xor(den, 8, 64);
    } else {
#pragma unroll
        for (int off = 1; off < 16; off <<= 1) den += __shfl_xor(den, off, 64);
    }
    if (eoff == 0) {
        minv[(size_t)node * H + h] = mm;
        dinv[(size_t)node * H + h] = 1.f / (den + 1e-16f);
    }
}

// ---------------- GAT aggregation: one wave per node, 2-edge software pipeline ----------------
// Two independent prefetch chains (A=even, B=odd edge) keep ~4 feature rows in flight
// per wave (vs 2 before) to cover the L2-miss latency of the random src gather.
template <int CHUNK, bool ELU, typename FT, typename OT>
__global__ void k_agg(const FT* __restrict__ feat, const int* __restrict__ offs,
                      const int* __restrict__ csr, const float* __restrict__ als,
                      const float* __restrict__ ald, const float* __restrict__ minv,
                      const float* __restrict__ dinv, const float* __restrict__ bias,
                      OT* __restrict__ out, int N) {
    constexpr int M = 64 * CHUNK;
    constexpr int H = M / 64;
    int lane = threadIdx.x & 63;
    int node = blockIdx.x * 4 + (threadIdx.x >> 6);
    if (node >= N) return;
    int head = (CHUNK == 4) ? (lane >> 4) : 0;
    float ad  = ald[(size_t)node * H + head];
    float m   = minv[(size_t)node * H + head];
    float inv = dinv[(size_t)node * H + head];
    int beg = offs[node], end = offs[node + 1];
    const FT* fb = feat + (size_t)lane * CHUNK;   // lane-fixed column offset

    float acc[CHUNK] = {};

    // prime chains A (edge beg) and B (edge beg+1, clamped)
    int   sA = csr[beg];
    int   sB = csr[(beg + 1 < end) ? beg + 1 : end - 1];
    float xA = als[(size_t)sA * H + head];
    float xB = als[(size_t)sB * H + head];
    float fA[CHUNK], fB[CHUNK];
    ldrow<CHUNK>(fb + (size_t)sA * M, fA);
    ldrow<CHUNK>(fb + (size_t)sB * M, fB);

    int e = beg;
    for (; e + 2 < end; e += 2) {
        // prefetch edges e+2, e+3 (e+3 clamped; duplicate load is harmless, not consumed)
        int   sA2 = csr[e + 2];
        int   sB2 = csr[(e + 3 < end) ? e + 3 : end - 1];
        float xA2 = als[(size_t)sA2 * H + head];
        float xB2 = als[(size_t)sB2 * H + head];
        float fA2[CHUNK], fB2[CHUNK];
        ldrow<CHUNK>(fb + (size_t)sA2 * M, fA2);
        ldrow<CHUNK>(fb + (size_t)sB2 * M, fB2);
        // consume edges e, e+1
        float a = xA + ad; a = (a > 0.f) ? a : 0.2f * a;
        float wa = __expf(a - m);
        float b = xB + ad; b = (b > 0.f) ? b : 0.2f * b;
        float wb = __expf(b - m);
#pragma unroll
        for (int j = 0; j < CHUNK; ++j) {
            acc[j] = fmaf(wa, fA[j], acc[j]);
            acc[j] = fmaf(wb, fB[j], acc[j]);
        }
        xA = xA2; xB = xB2;
#pragma unroll
        for (int j = 0; j < CHUNK; ++j) { fA[j] = fA2[j]; fB[j] = fB2[j]; }
    }
    // tail: 1 or 2 edges left
    {
        float a = xA + ad; a = (a > 0.f) ? a : 0.2f * a;
        float wa = __expf(a - m);
#pragma unroll
        for (int j = 0; j < CHUNK; ++j) acc[j] = fmaf(wa, fA[j], acc[j]);
        if (e + 1 < end) {
            float b = xB + ad; b = (b > 0.f) ? b : 0.2f * b;
            float wb = __expf(b - m);
#pragma unroll
            for (int j = 0; j < CHUNK; ++j) acc[j] = fmaf(wb, fB[j], acc[j]);
        }
    }
#pragma unroll
    for (int j = 0; j < CHUNK; ++j) {
        int col = lane * CHUNK + j;
        float v = acc[j] * inv + bias[col];
        if (ELU) v = (v > 0.f) ? v : (__expf(v) - 1.f);
        st(&out[(size_t)node * M + col], v);
    }
}

// ---------------- global mean pool: batch sorted -> one block per graph ----------------
static __device__ __forceinline__ int lowerb(const int* __restrict__ a, int n, int v) {
    int lo = 0, hi = n;
    while (lo < hi) { int mid = (lo + hi) >> 1; if (a[mid] < v) lo = mid + 1; else hi = mid; }
    return lo;
}

__global__ void k_pool2(const float* __restrict__ ne, const int* __restrict__ batch,
                        float* __restrict__ gout, int N) {
    int g = blockIdx.x;
    int lo = lowerb(batch, N, g);
    int hi = lowerb(batch, N, g + 1);
    int lane = threadIdx.x & 63, row = threadIdx.x >> 6;
    float s = 0.f;
    for (int i = lo + row; i < hi; i += 4) s += ne[(size_t)i * 64 + lane];
    __shared__ float red[4][64];
    red[row][lane] = s;
    __syncthreads();
    if (row == 0) {
        float v = red[0][lane] + red[1][lane] + red[2][lane] + red[3][lane];
        gout[(size_t)g * 64 + lane] = v / fmaxf((float)(hi - lo), 1.f);
    }
}

extern "C" void kernel_launch(void* const* d_in, const int* in_sizes, int n_in,
                              void* d_out, int out_size, void* d_ws, size_t ws_size,
                              hipStream_t stream) {
    const float* x   = (const float*)d_in[0];
    const int* ei    = (const int*)d_in[1];
    const int* batch = (const int*)d_in[2];
    const float* W1  = (const float*)d_in[3];
    const float* as1 = (const float*)d_in[4];
    const float* ad1 = (const float*)d_in[5];
    const float* b1  = (const float*)d_in[6];
    const float* W2  = (const float*)d_in[7];
    const float* as2 = (const float*)d_in[8];
    const float* ad2 = (const float*)d_in[9];
    const float* b2  = (const float*)d_in[10];
    const float* W3  = (const float*)d_in[11];
    const float* as3 = (const float*)d_in[12];
    const float* ad3 = (const float*)d_in[13];
    const float* b3  = (const float*)d_in[14];

    const int N = in_sizes[2];      // 50000
    const int E = in_sizes[1] / 2;  // 800000
    const int G = 64;
    float* out = (float*)d_out;

    // workspace (~58 MB)
    char* w = (char*)d_ws;
    auto carve = [&](size_t bytes) { char* p = w; w += (bytes + 255) & ~(size_t)255; return p; };
    __half* feat = (__half*)carve((size_t)N * 256 * 2);
    __half* act  = (__half*)carve((size_t)N * 256 * 2);
    float* als   = (float*)carve((size_t)N * 4 * 4);
    float* ald   = (float*)carve((size_t)N * 4 * 4);
    float* minv  = (float*)carve((size_t)N * 4 * 4);
    float* dinv  = (float*)carve((size_t)N * 4 * 4);
    int* deg     = (int*)carve((size_t)N * 4);
    int* offs    = (int*)carve((size_t)(N + 1) * 4);
    int* cursor  = (int*)carve((size_t)N * 4);
    int* csr     = (int*)carve((size_t)(E + N) * 4);
    int nb       = (N + 255) / 256;
    int* bsum    = (int*)carve((size_t)(nb + 1) * 4);

    k_init<<<(N + 255) / 256, 256, 0, stream>>>(deg, N);
    k_hist<<<(E + 255) / 256, 256, 0, stream>>>(ei, deg, E);
    k_scan1<<<nb, 256, 0, stream>>>(deg, offs, bsum, N);
    k_scan2<<<1, 256, 0, stream>>>(bsum, nb);
    k_scan3<<<nb, 256, 0, stream>>>(offs, cursor, bsum, N, nb);
    k_scatter<<<(E + 255) / 256, 256, 0, stream>>>(ei, cursor, csr, E);
    k_scatter_loops<<<(N + 255) / 256, 256, 0, stream>>>(cursor, csr, N);

    dim3 gemmBig((N + 127) / 128, 4);
    dim3 gemmSmall((N + 127) / 128, 1);
    int nodeBlocks = (N + 3) / 4;
    int mdBlocks   = (N + 15) / 16;

    // layer 1
    k_gemm_mfma<float><<<gemmBig, 256, 0, stream>>>(x, W1, feat, N, 256, 256);
    k_alpha<4, __half><<<nodeBlocks, 256, 0, stream>>>(feat, as1, ad1, als, ald, N);
    k_maxden<4><<<mdBlocks, 256, 0, stream>>>(offs, csr, als, ald, minv, dinv, N);
    k_agg<4, true, __half, __half><<<nodeBlocks, 256, 0, stream>>>(feat, offs, csr, als, ald, minv, dinv, b1, act, N);
    // layer 2
    k_gemm_mfma<__half><<<gemmBig, 256, 0, stream>>>(act, W2, feat, N, 256, 256);
    k_alpha<4, __half><<<nodeBlocks, 256, 0, stream>>>(feat, as2, ad2, als, ald, N);
    k_maxden<4><<<mdBlocks, 256, 0, stream>>>(offs, csr, als, ald, minv, dinv, N);
    k_agg<4, true, __half, __half><<<nodeBlocks, 256, 0, stream>>>(feat, offs, csr, als, ald, minv, dinv, b2, act, N);
    // layer 3: 256 -> 64, single head, no ELU
    k_gemm_mfma<__half><<<gemmSmall, 256, 0, stream>>>(act, W3, feat, N, 256, 64);
    k_alpha<1, __half><<<nodeBlocks, 256, 0, stream>>>(feat, as3, ad3, als, ald, N);
    k_maxden<1><<<mdBlocks, 256, 0, stream>>>(offs, csr, als, ald, minv, dinv, N);
    k_agg<1, false, __half, float><<<nodeBlocks, 256, 0, stream>>>(feat, offs, csr, als, ald, minv, dinv, b3, out, N);

    // global mean pool
    k_pool2<<<G, 256, 0, stream>>>(out, batch, out + (size_t)N * 64, N);
}